// Round 6
// baseline (2651.451 us; speedup 1.0000x reference)
//
#include <hip/hip_runtime.h>
#include <cstdint>
#include <cstddef>
#include <cstring>

#define T_SEQ 512
#define NB 32
#define POLL_FAST 100

__device__ __forceinline__ uint32_t agent_load_u32(const uint32_t* p) {
    return __hip_atomic_load(p, __ATOMIC_RELAXED, __HIP_MEMORY_SCOPE_AGENT);
}
__device__ __forceinline__ void agent_store_u32(uint32_t* p, uint32_t v) {
    __hip_atomic_store(p, v, __ATOMIC_RELAXED, __HIP_MEMORY_SCOPE_AGENT);
}

// =====================================================================
// GEMM: C[M,N] = A[M,K] @ W[N,K]^T + (bi+bh)[N]   (unchanged, proven r2)
// =====================================================================
#define BM 64
#define BN 128
#define BK 32
#define AS_STRIDE 68
#define BS_STRIDE 132

__global__ __launch_bounds__(256, 4) void gemm_xp(
    const float* __restrict__ A, const float* __restrict__ W,
    const float* __restrict__ bi, const float* __restrict__ bh,
    float* __restrict__ C, int M, int N, int K)
{
    __shared__ float As[BK][AS_STRIDE];
    __shared__ float Bs[BK][BS_STRIDE];

    const int tid = threadIdx.x;
    const int tx = tid & 15;
    const int ty = tid >> 4;
    const int m0 = blockIdx.x * BM;
    const int n0 = blockIdx.y * BN;
    const int lr = tid >> 3;
    const int lc = (tid & 7) << 2;

    float acc[4][8];
#pragma unroll
    for (int i = 0; i < 4; i++)
#pragma unroll
        for (int j = 0; j < 8; j++) acc[i][j] = 0.f;

    for (int k0 = 0; k0 < K; k0 += BK) {
#pragma unroll
        for (int p = 0; p < 2; p++) {
            const int m = p * 32 + lr;
            const float4 a4 = *(const float4*)(A + (size_t)(m0 + m) * K + k0 + lc);
            As[lc + 0][m] = a4.x; As[lc + 1][m] = a4.y;
            As[lc + 2][m] = a4.z; As[lc + 3][m] = a4.w;
        }
#pragma unroll
        for (int p = 0; p < 4; p++) {
            const int n = p * 32 + lr;
            const float4 b4 = *(const float4*)(W + (size_t)(n0 + n) * K + k0 + lc);
            Bs[lc + 0][n] = b4.x; Bs[lc + 1][n] = b4.y;
            Bs[lc + 2][n] = b4.z; Bs[lc + 3][n] = b4.w;
        }
        __syncthreads();

#pragma unroll
        for (int kk = 0; kk < BK; kk++) {
            const float4 a4  = *(const float4*)&As[kk][tx << 2];
            const float4 b4a = *(const float4*)&Bs[kk][ty << 3];
            const float4 b4b = *(const float4*)&Bs[kk][(ty << 3) + 4];
            const float a[4] = { a4.x, a4.y, a4.z, a4.w };
            const float b[8] = { b4a.x, b4a.y, b4a.z, b4a.w,
                                 b4b.x, b4b.y, b4b.z, b4b.w };
#pragma unroll
            for (int i = 0; i < 4; i++)
#pragma unroll
                for (int j = 0; j < 8; j++)
                    acc[i][j] = fmaf(a[i], b[j], acc[i][j]);
        }
        __syncthreads();
    }

    const int nbase = n0 + (ty << 3);
    const float4 bia = *(const float4*)(bi + nbase);
    const float4 bib = *(const float4*)(bi + nbase + 4);
    const float4 bha = *(const float4*)(bh + nbase);
    const float4 bhb = *(const float4*)(bh + nbase + 4);
    const float bt[8] = { bia.x + bha.x, bia.y + bha.y, bia.z + bha.z, bia.w + bha.w,
                          bib.x + bhb.x, bib.y + bhb.y, bib.z + bhb.z, bib.w + bhb.w };
#pragma unroll
    for (int i = 0; i < 4; i++) {
        const int row = m0 + (tx << 2) + i;
        float4 o1, o2;
        o1.x = acc[i][0] + bt[0]; o1.y = acc[i][1] + bt[1];
        o1.z = acc[i][2] + bt[2]; o1.w = acc[i][3] + bt[3];
        o2.x = acc[i][4] + bt[4]; o2.y = acc[i][5] + bt[5];
        o2.z = acc[i][6] + bt[6]; o2.w = acc[i][7] + bt[7];
        *(float4*)(C + (size_t)row * N + nbase)     = o1;
        *(float4*)(C + (size_t)row * N + nbase + 4) = o2;
    }
}

// =====================================================================
// Recurrence, H=512 (layers 0,1). 128 blocks = 4 slices x 32 batches.
// Thread (jl=tid&127, kq=tid>>7) holds W_hh[s*128+jl][kq*128..+127] in
// VGPRs. Weights loaded via volatile uint64_t scalars: volatile loads
// cannot be rematerialized/sunk into the t-loop, forcing true register
// residency (r1/r2 VGPR counts proved the compiler restreams otherwise).
//
// h exchange: parity-double-buffered self-validating words
//   slot[(t+1)&1][row] = (fp16(h)<<16) | ((tagbase+t+1)&0xffff)
// published to TWO disjoint arrays:
//   fast: volatile store/poll (sc0 -> shared XCD L2; valid if producer
//         and consumer share an XCD — usually true for block=s*32+b)
//   slow: relaxed agent-scope atomics (LLC; always valid)
// Disjoint lines => no dirty-L2 writeback can clobber an agent store.
// Consumer: bounded fast burst, then agent poll (guaranteed progress =>
// no hang under any mapping). After agent-detect, one fast re-probe;
// 8 consecutive misses => cross-XCD => disable burst.
// Overwrite-before-read impossible: producer writes tag t+3 into parity
// slot only after its step t+2, which transitively requires every
// consumer to have already consumed tag t+1 from that slot.
// =====================================================================
__global__ __launch_bounds__(512, 2) void rec_h512(
    const float* __restrict__ Whh,    // [512,512] fp32
    float* __restrict__ xpseq,        // [NB, T, 512] in: xp, out: relu(h)
    uint32_t* __restrict__ hpk_fast,  // [NB][2][512]
    uint32_t* __restrict__ hpk_slow,  // [NB][2][512]
    int tagbase)
{
    const int tid = threadIdx.x;
    const int b  = blockIdx.x & 31;
    const int s  = blockIdx.x >> 5;
    const int jl = tid & 127;
    const int kq = tid >> 7;         // wave-uniform
    const bool own = (kq == s);

    __shared__ float hbuf[2][512];
    __shared__ float part[4][128];

    // ---- weights: 128 fp32 pinned in VGPRs (volatile u64 loads) ----
    float w[128];
    {
        const volatile uint64_t* wp =
            (const volatile uint64_t*)(Whh + (size_t)((s << 7) + jl) * 512 + (kq << 7));
#pragma unroll
        for (int i = 0; i < 64; i++) {
            const uint64_t u = wp[i];
            float f2[2]; __builtin_memcpy(f2, &u, 8);
            w[2 * i] = f2[0]; w[2 * i + 1] = f2[1];
        }
    }

    uint32_t* fast_b = hpk_fast + (b << 10);   // [2][512]
    uint32_t* slow_b = hpk_slow + (b << 10);   // [2][512]
    float* xp_b = xpseq + (size_t)b * (T_SEQ * 512);
    const int myrow = (s << 7) + tid;          // publisher row (tid<128)

    float xpv = (tid < 128) ? xp_b[myrow] : 0.f;
    int vol_fails = 0;
    bool vol_ok = true;

    for (int t = 0; t < T_SEQ; t++) {
        const int p = t & 1;
        float xpn = (tid < 128 && t + 1 < T_SEQ) ? xp_b[(t + 1) * 512 + myrow] : 0.f;

        float a0 = 0.f, a1 = 0.f, a2 = 0.f, a3 = 0.f;
        if (t > 0) {
            if (!own) {
                const uint32_t wtag = (uint32_t)((tagbase + t) & 0xffff);
                const volatile uint32_t* vf = (const volatile uint32_t*)(fast_b + (p << 9) + tid);
                uint32_t* sp = slow_b + (p << 9) + tid;
                uint32_t v = 0;
                bool got = false;
                if (vol_ok) {
                    for (int k = 0; k < POLL_FAST; ++k) {
                        v = *vf;
                        if ((v & 0xffffu) == wtag) { got = true; break; }
                    }
                }
                if (!got) {
                    for (;;) {
                        v = agent_load_u32(sp);
                        if ((v & 0xffffu) == wtag) break;
                    }
                    if (vol_ok) {          // probe: is the fast route live?
                        const uint32_t vv = *vf;
                        if ((vv & 0xffffu) != wtag) {
                            if (++vol_fails >= 8) vol_ok = false;
                        } else vol_fails = 0;
                    }
                } else vol_fails = 0;
                const unsigned short us = (unsigned short)(v >> 16);
                _Float16 hf; __builtin_memcpy(&hf, &us, 2);
                hbuf[p][tid] = (float)hf;
            }
            __syncthreads();   // B1: hbuf[p] complete (decode + prev epilogue)
            const float4* hq = (const float4*)(&hbuf[p][kq << 7]);
#pragma unroll
            for (int i = 0; i < 32; i++) {
                const float4 h4 = hq[i];
                a0 = fmaf(w[4 * i + 0], h4.x, a0);
                a1 = fmaf(w[4 * i + 1], h4.y, a1);
                a2 = fmaf(w[4 * i + 2], h4.z, a2);
                a3 = fmaf(w[4 * i + 3], h4.w, a3);
            }
        }
        part[kq][jl] = (a0 + a1) + (a2 + a3);
        __syncthreads();       // B2: parts ready
        if (tid < 128) {
            const int p2 = (t + 1) & 1;
            const float v = part[0][tid] + part[1][tid] + part[2][tid] + part[3][tid] + xpv;
            const float hv = tanhf(v);
            _Float16 hf = (_Float16)hv;
            unsigned short us; __builtin_memcpy(&us, &hf, 2);
            const uint32_t pkv = ((uint32_t)us << 16) | (uint32_t)((tagbase + t + 1) & 0xffff);
            *(volatile uint32_t*)(fast_b + (p2 << 9) + myrow) = pkv;  // XCD L2
            agent_store_u32(slow_b + (p2 << 9) + myrow, pkv);         // LLC
            hbuf[p2][myrow] = (float)hf;               // own-slice fast path
            xp_b[t * 512 + myrow] = fmaxf(hv, 0.f);
        }
        xpv = xpn;
        // no trailing barrier: next step's B1 orders part[]/hbuf reuse
    }
}

// =====================================================================
// Recurrence, H=128 (layer 2). One WG per batch; LDS-only.
// Volatile u64 weight loads pin W in VGPRs.
// =====================================================================
__global__ __launch_bounds__(256, 4) void rec_h128(
    const float* __restrict__ Whh,   // [128,128]
    const float* __restrict__ xp,    // [NB, T, 128]
    float* __restrict__ out,         // [NB, T, 128]
    float* __restrict__ hn)          // [NB, 128]
{
    const int tid = threadIdx.x;
    const int b  = blockIdx.x;
    const int j  = tid & 127;
    const int kh = tid >> 7;

    __shared__ float hbuf[2][128];
    __shared__ float part[2][128];

    float w[64];
    {
        const volatile uint64_t* wp =
            (const volatile uint64_t*)(Whh + (size_t)j * 128 + (kh << 6));
#pragma unroll
        for (int i = 0; i < 32; i++) {
            const uint64_t u = wp[i];
            float f2[2]; __builtin_memcpy(f2, &u, 8);
            w[2 * i] = f2[0]; w[2 * i + 1] = f2[1];
        }
    }

    const float* xp_b = xp + (size_t)b * (T_SEQ * 128);
    float* out_b = out + (size_t)b * (T_SEQ * 128);

    float xpv = (tid < 128) ? xp_b[tid] : 0.f;

    for (int t = 0; t < T_SEQ; t++) {
        float xpn = (tid < 128 && t + 1 < T_SEQ) ? xp_b[(t + 1) * 128 + tid] : 0.f;

        float a0 = 0.f, a1 = 0.f, a2 = 0.f, a3 = 0.f;
        if (t > 0) {
            const float4* hq = (const float4*)(&hbuf[t & 1][kh << 6]);
#pragma unroll
            for (int i = 0; i < 16; i++) {
                const float4 h4 = hq[i];
                a0 = fmaf(w[4 * i + 0], h4.x, a0);
                a1 = fmaf(w[4 * i + 1], h4.y, a1);
                a2 = fmaf(w[4 * i + 2], h4.z, a2);
                a3 = fmaf(w[4 * i + 3], h4.w, a3);
            }
        }
        part[kh][j] = (a0 + a1) + (a2 + a3);
        __syncthreads();
        if (tid < 128) {
            const float v = part[0][tid] + part[1][tid] + xpv;
            const float h = tanhf(v);
            hbuf[(t + 1) & 1][tid] = h;
            out_b[t * 128 + tid] = h;
            if (t == T_SEQ - 1) hn[b * 128 + tid] = h;
        }
        __syncthreads();
        xpv = xpn;
    }
}

// =====================================================================
// Launch
// =====================================================================
extern "C" void kernel_launch(void* const* d_in, const int* in_sizes, int n_in,
                              void* d_out, int out_size, void* d_ws, size_t ws_size,
                              hipStream_t stream)
{
    const float* x    = (const float*)d_in[0];
    const float* Wih0 = (const float*)d_in[1];
    const float* Whh0 = (const float*)d_in[2];
    const float* bih0 = (const float*)d_in[3];
    const float* bhh0 = (const float*)d_in[4];
    const float* Wih1 = (const float*)d_in[5];
    const float* Whh1 = (const float*)d_in[6];
    const float* bih1 = (const float*)d_in[7];
    const float* bhh1 = (const float*)d_in[8];
    const float* Wih2 = (const float*)d_in[9];
    const float* Whh2 = (const float*)d_in[10];
    const float* bih2 = (const float*)d_in[11];
    const float* bhh2 = (const float*)d_in[12];

    float* ws   = (float*)d_ws;
    float* buf0 = ws;                      // 8388608 f
    float* buf1 = ws + 8388608;            // 8388608 f
    float* xp2  = ws + 16777216;           // 2097152 f
    uint32_t* hpk_fast = (uint32_t*)(ws + 18874368); // [32][2][512] = 32768 w
    uint32_t* hpk_slow = hpk_fast + 32768;           // [32][2][512] = 32768 w

    float* out = (float*)d_out;            // [32,512,128]
    float* hn  = out + NB * T_SEQ * 128;   // [1,32,128]

    const int M = NB * T_SEQ;  // 16384

    // layer 0
    gemm_xp<<<dim3(M / BM, 512 / BN), 256, 0, stream>>>(x, Wih0, bih0, bhh0, buf0, M, 512, 128);
    rec_h512<<<NB * 4, 512, 0, stream>>>(Whh0, buf0, hpk_fast, hpk_slow, 0);
    // layer 1
    gemm_xp<<<dim3(M / BM, 512 / BN), 256, 0, stream>>>(buf0, Wih1, bih1, bhh1, buf1, M, 512, 512);
    rec_h512<<<NB * 4, 512, 0, stream>>>(Whh1, buf1, hpk_fast, hpk_slow, 1024);
    // layer 2
    gemm_xp<<<dim3(M / BM, 128 / BN), 256, 0, stream>>>(buf1, Wih2, bih2, bhh2, xp2, M, 128, 512);
    rec_h128<<<NB, 256, 0, stream>>>(Whh2, xp2, out, hn);
}

// Round 7
// 1988.334 us; speedup vs baseline: 1.3335x; 1.3335x over previous
//
#include <hip/hip_runtime.h>
#include <hip/hip_fp16.h>
#include <cstdint>
#include <cstddef>
#include <cstring>

#define T_SEQ 512
#define NB 32

__device__ __forceinline__ uint32_t agent_load_u32(const uint32_t* p) {
    return __hip_atomic_load(p, __ATOMIC_RELAXED, __HIP_MEMORY_SCOPE_AGENT);
}
__device__ __forceinline__ void agent_store_u32(uint32_t* p, uint32_t v) {
    __hip_atomic_store(p, v, __ATOMIC_RELAXED, __HIP_MEMORY_SCOPE_AGENT);
}

// =====================================================================
// GEMM: C[M,N] = A[M,K] @ W[N,K]^T + (bi+bh)[N]   (unchanged, proven r2)
// =====================================================================
#define BM 64
#define BN 128
#define BK 32
#define AS_STRIDE 68
#define BS_STRIDE 132

__global__ __launch_bounds__(256, 4) void gemm_xp(
    const float* __restrict__ A, const float* __restrict__ W,
    const float* __restrict__ bi, const float* __restrict__ bh,
    float* __restrict__ C, int M, int N, int K)
{
    __shared__ float As[BK][AS_STRIDE];
    __shared__ float Bs[BK][BS_STRIDE];

    const int tid = threadIdx.x;
    const int tx = tid & 15;
    const int ty = tid >> 4;
    const int m0 = blockIdx.x * BM;
    const int n0 = blockIdx.y * BN;
    const int lr = tid >> 3;
    const int lc = (tid & 7) << 2;

    float acc[4][8];
#pragma unroll
    for (int i = 0; i < 4; i++)
#pragma unroll
        for (int j = 0; j < 8; j++) acc[i][j] = 0.f;

    for (int k0 = 0; k0 < K; k0 += BK) {
#pragma unroll
        for (int p = 0; p < 2; p++) {
            const int m = p * 32 + lr;
            const float4 a4 = *(const float4*)(A + (size_t)(m0 + m) * K + k0 + lc);
            As[lc + 0][m] = a4.x; As[lc + 1][m] = a4.y;
            As[lc + 2][m] = a4.z; As[lc + 3][m] = a4.w;
        }
#pragma unroll
        for (int p = 0; p < 4; p++) {
            const int n = p * 32 + lr;
            const float4 b4 = *(const float4*)(W + (size_t)(n0 + n) * K + k0 + lc);
            Bs[lc + 0][n] = b4.x; Bs[lc + 1][n] = b4.y;
            Bs[lc + 2][n] = b4.z; Bs[lc + 3][n] = b4.w;
        }
        __syncthreads();

#pragma unroll
        for (int kk = 0; kk < BK; kk++) {
            const float4 a4  = *(const float4*)&As[kk][tx << 2];
            const float4 b4a = *(const float4*)&Bs[kk][ty << 3];
            const float4 b4b = *(const float4*)&Bs[kk][(ty << 3) + 4];
            const float a[4] = { a4.x, a4.y, a4.z, a4.w };
            const float b[8] = { b4a.x, b4a.y, b4a.z, b4a.w,
                                 b4b.x, b4b.y, b4b.z, b4b.w };
#pragma unroll
            for (int i = 0; i < 4; i++)
#pragma unroll
                for (int j = 0; j < 8; j++)
                    acc[i][j] = fmaf(a[i], b[j], acc[i][j]);
        }
        __syncthreads();
    }

    const int nbase = n0 + (ty << 3);
    const float4 bia = *(const float4*)(bi + nbase);
    const float4 bib = *(const float4*)(bi + nbase + 4);
    const float4 bha = *(const float4*)(bh + nbase);
    const float4 bhb = *(const float4*)(bh + nbase + 4);
    const float bt[8] = { bia.x + bha.x, bia.y + bha.y, bia.z + bha.z, bia.w + bha.w,
                          bib.x + bhb.x, bib.y + bhb.y, bib.z + bhb.z, bib.w + bhb.w };
#pragma unroll
    for (int i = 0; i < 4; i++) {
        const int row = m0 + (tx << 2) + i;
        float4 o1, o2;
        o1.x = acc[i][0] + bt[0]; o1.y = acc[i][1] + bt[1];
        o1.z = acc[i][2] + bt[2]; o1.w = acc[i][3] + bt[3];
        o2.x = acc[i][4] + bt[4]; o2.y = acc[i][5] + bt[5];
        o2.z = acc[i][6] + bt[6]; o2.w = acc[i][7] + bt[7];
        *(float4*)(C + (size_t)row * N + nbase)     = o1;
        *(float4*)(C + (size_t)row * N + nbase + 4) = o2;
    }
}

// =====================================================================
// Recurrence, H=512 (layers 0,1).
// 256 blocks = 8 slices x 32 batches (block = s*32+b), 512 threads,
// 1 block/CU -> co-residency guaranteed. Thread (jl=tid&63, kq=tid>>6)
// holds W_hh[s*64+jl][kq*64..+63] as fp16: __half2 w[32] = 32 VGPRs.
// Total pressure ~70 regs — BELOW the compiler's ~92 pressure target
// (r2/r6 evidence), so the weight values stay hoisted/resident: no
// per-step L2 restream (r2's dominant cost) and no scratch spill (r6's).
// Compute: fmaf(__low2float(w), h, acc) -> v_fma_mix_f32.
//
// h exchange (proven r6): parity-double-buffered self-validating words
//   hpk[b][(t+1)&1][row] = (fp16(h)<<16) | ((tagbase+t+1)&0xffff)
// relaxed agent-scope atomics (LLC). Overwrite-before-read impossible:
// producer writes tag t+2 into a parity slot only after its step t+1
// decode, which requires every block's step-t+1 tags, which requires all
// consumers already consumed tag t from that slot. Workspace poison
// 0xAAAA never matches a live tag.
// =====================================================================
__global__ __launch_bounds__(512, 2) void rec_h512(
    const float* __restrict__ Whh,    // [512,512] fp32
    float* __restrict__ xpseq,        // [NB, T, 512] in: xp, out: relu(h)
    uint32_t* __restrict__ hpk,       // [NB][2][512] packed h words
    int tagbase)
{
    const int tid = threadIdx.x;
    const int b  = blockIdx.x & 31;
    const int s  = blockIdx.x >> 5;   // 0..7
    const int jl = tid & 63;          // row within slice
    const int kq = tid >> 6;          // 0..7, wave-uniform (wave = 64 lanes)
    const bool own = (kq == s);       // wave s's rows are this block's outputs

    __shared__ float hbuf[2][512];
    __shared__ float part[8][64];

    // ---- weights: 64 fp16 packed into 32 half2 regs ----
    __half2 w[32];
    {
        const float4* wp4 = (const float4*)(Whh + (size_t)((s << 6) + jl) * 512 + (kq << 6));
#pragma unroll
        for (int i = 0; i < 16; i++) {
            const float4 v = wp4[i];
            w[2 * i]     = __floats2half2_rn(v.x, v.y);
            w[2 * i + 1] = __floats2half2_rn(v.z, v.w);
        }
    }

    uint32_t* hp_b = hpk + (b << 10);                 // [2][512]
    float* xp_b = xpseq + (size_t)b * (T_SEQ * 512);
    const int myrow = (s << 6) + tid;                 // valid for tid<64

    float xpv = (tid < 64) ? xp_b[myrow] : 0.f;

    for (int t = 0; t < T_SEQ; t++) {
        const int p = t & 1;
        float xpn = (tid < 64 && t + 1 < T_SEQ) ? xp_b[(t + 1) * 512 + myrow] : 0.f;

        float a0 = 0.f, a1 = 0.f, a2 = 0.f, a3 = 0.f;
        if (t > 0) {
            if (!own) {
                const uint32_t wtag = (uint32_t)((tagbase + t) & 0xffff);
                uint32_t* sp = hp_b + (p << 9) + tid;
                uint32_t v;
                do { v = agent_load_u32(sp); } while ((v & 0xffffu) != wtag);
                const unsigned short us = (unsigned short)(v >> 16);
                _Float16 hf; __builtin_memcpy(&hf, &us, 2);
                hbuf[p][tid] = (float)hf;
            }
            __syncthreads();   // B1: hbuf[p] complete; also orders part[] reuse
            const float4* hq = (const float4*)(&hbuf[p][kq << 6]);
#pragma unroll
            for (int i = 0; i < 16; i++) {
                const float4 h4 = hq[i];   // broadcast: kq wave-uniform
                a0 = fmaf(__low2float(w[2 * i]),      h4.x, a0);
                a1 = fmaf(__high2float(w[2 * i]),     h4.y, a1);
                a2 = fmaf(__low2float(w[2 * i + 1]),  h4.z, a2);
                a3 = fmaf(__high2float(w[2 * i + 1]), h4.w, a3);
            }
        }
        part[kq][jl] = (a0 + a1) + (a2 + a3);
        __syncthreads();       // B2: parts ready
        if (tid < 64) {        // wave 0 = epilogue
            const int p2 = (t + 1) & 1;
            float v = xpv;
#pragma unroll
            for (int q = 0; q < 8; q++) v += part[q][tid];
            const float hv = tanhf(v);
            _Float16 hf = (_Float16)hv;
            unsigned short us; __builtin_memcpy(&us, &hf, 2);
            const uint32_t pkv = ((uint32_t)us << 16) | (uint32_t)((tagbase + t + 1) & 0xffff);
            agent_store_u32(hp_b + (p2 << 9) + myrow, pkv);
            hbuf[p2][myrow] = (float)hf;              // own-slice fast path
            xp_b[t * 512 + myrow] = fmaxf(hv, 0.f);
        }
        xpv = xpn;
        // no trailing barrier: next step's B1 orders everything
    }
}

// =====================================================================
// Recurrence, H=128 (layer 2). One WG per batch; LDS-only. (proven r2)
// =====================================================================
__global__ __launch_bounds__(256, 4) void rec_h128(
    const float* __restrict__ Whh,   // [128,128]
    const float* __restrict__ xp,    // [NB, T, 128]
    float* __restrict__ out,         // [NB, T, 128]
    float* __restrict__ hn)          // [NB, 128]
{
    const int tid = threadIdx.x;
    const int b  = blockIdx.x;
    const int j  = tid & 127;
    const int kh = tid >> 7;

    __shared__ float hbuf[2][128];
    __shared__ float part[2][128];

    float w[64];
    {
        const float4* wp = (const float4*)(Whh + (size_t)j * 128 + (kh << 6));
#pragma unroll
        for (int i = 0; i < 16; i++) {
            const float4 v = wp[i];
            w[4 * i + 0] = v.x; w[4 * i + 1] = v.y;
            w[4 * i + 2] = v.z; w[4 * i + 3] = v.w;
        }
    }

    const float* xp_b = xp + (size_t)b * (T_SEQ * 128);
    float* out_b = out + (size_t)b * (T_SEQ * 128);

    float xpv = (tid < 128) ? xp_b[tid] : 0.f;

    for (int t = 0; t < T_SEQ; t++) {
        float xpn = (tid < 128 && t + 1 < T_SEQ) ? xp_b[(t + 1) * 128 + tid] : 0.f;

        float a0 = 0.f, a1 = 0.f, a2 = 0.f, a3 = 0.f;
        if (t > 0) {
            const float4* hq = (const float4*)(&hbuf[t & 1][kh << 6]);
#pragma unroll
            for (int i = 0; i < 16; i++) {
                const float4 h4 = hq[i];
                a0 = fmaf(w[4 * i + 0], h4.x, a0);
                a1 = fmaf(w[4 * i + 1], h4.y, a1);
                a2 = fmaf(w[4 * i + 2], h4.z, a2);
                a3 = fmaf(w[4 * i + 3], h4.w, a3);
            }
        }
        part[kh][j] = (a0 + a1) + (a2 + a3);
        __syncthreads();
        if (tid < 128) {
            const float v = part[0][tid] + part[1][tid] + xpv;
            const float h = tanhf(v);
            hbuf[(t + 1) & 1][tid] = h;
            out_b[t * 128 + tid] = h;
            if (t == T_SEQ - 1) hn[b * 128 + tid] = h;
        }
        __syncthreads();
        xpv = xpn;
    }
}

// =====================================================================
// Launch
// =====================================================================
extern "C" void kernel_launch(void* const* d_in, const int* in_sizes, int n_in,
                              void* d_out, int out_size, void* d_ws, size_t ws_size,
                              hipStream_t stream)
{
    const float* x    = (const float*)d_in[0];
    const float* Wih0 = (const float*)d_in[1];
    const float* Whh0 = (const float*)d_in[2];
    const float* bih0 = (const float*)d_in[3];
    const float* bhh0 = (const float*)d_in[4];
    const float* Wih1 = (const float*)d_in[5];
    const float* Whh1 = (const float*)d_in[6];
    const float* bih1 = (const float*)d_in[7];
    const float* bhh1 = (const float*)d_in[8];
    const float* Wih2 = (const float*)d_in[9];
    const float* Whh2 = (const float*)d_in[10];
    const float* bih2 = (const float*)d_in[11];
    const float* bhh2 = (const float*)d_in[12];

    float* ws   = (float*)d_ws;
    float* buf0 = ws;                      // 8388608 f
    float* buf1 = ws + 8388608;            // 8388608 f
    float* xp2  = ws + 16777216;           // 2097152 f
    uint32_t* hpk = (uint32_t*)(ws + 18874368); // [32][2][512] = 32768 words

    float* out = (float*)d_out;            // [32,512,128]
    float* hn  = out + NB * T_SEQ * 128;   // [1,32,128]

    const int M = NB * T_SEQ;  // 16384

    // layer 0
    gemm_xp<<<dim3(M / BM, 512 / BN), 256, 0, stream>>>(x, Wih0, bih0, bhh0, buf0, M, 512, 128);
    rec_h512<<<NB * 8, 512, 0, stream>>>(Whh0, buf0, hpk, 0);
    // layer 1
    gemm_xp<<<dim3(M / BM, 512 / BN), 256, 0, stream>>>(buf0, Wih1, bih1, bhh1, buf1, M, 512, 512);
    rec_h512<<<NB * 8, 512, 0, stream>>>(Whh1, buf1, hpk, 1024);
    // layer 2
    gemm_xp<<<dim3(M / BM, 128 / BN), 256, 0, stream>>>(buf1, Wih2, bih2, bhh2, xp2, M, 128, 512);
    rec_h128<<<NB, 256, 0, stream>>>(Whh2, xp2, out, hn);
}